// Round 1
// baseline (8821.154 us; speedup 1.0000x reference)
//
#include <hip/hip_runtime.h>
#include <math.h>

#define TT 512
#define BB 256
#define OBS 128
#define HH 64
#define G3 192
#define NROW (TT*BB)

// ---------------------------------------------------------------------------
// Fused input-projection + sequential GRU scan.
// One block per batch element b. 256 threads:
//   tau in [0,192): "g-threads": hold w_ih[g,:] (128 VGPR) and w_hh[g,:]
//                   (64 VGPR) in registers; compute gi_g and gh_g each step.
//   tau in [192,256): helpers: double-buffer next timestep's x row into LDS.
// Gate math (r,z,n, sign) on threads 0..63. All f32 (sign() demands ~1e-6
// accuracy upstream; bf16/MFMA would flip signs and blow the threshold).
// ---------------------------------------------------------------------------
__global__ __launch_bounds__(256, 1)
void scan_kernel(const float* __restrict__ x, const float* __restrict__ h0,
                 const float* __restrict__ done,
                 const float* __restrict__ w_ih, const float* __restrict__ w_hh,
                 const float* __restrict__ b_ih, const float* __restrict__ b_hh,
                 signed char* __restrict__ hidden, float* __restrict__ state_out)
{
    const int b   = blockIdx.x;
    const int tau = threadIdx.x;

    __shared__ __align__(16) float xb[2][OBS];   // double-buffered x row
    __shared__ __align__(16) float hb[HH];       // masked carried state
    __shared__ __align__(16) float srz[2*HH];    // r,z pre-activations (gi+gh)
    __shared__ __align__(16) float sinb[HH];     // i_n
    __shared__ __align__(16) float shnb[HH];     // h_n

    float wi[OBS];
    float wh[HH];
    float bi = 0.f, bh = 0.f;
    if (tau < G3) {
        const float4* wi4 = (const float4*)(w_ih + tau*OBS);
        #pragma unroll
        for (int k4 = 0; k4 < OBS/4; ++k4) {
            float4 v = wi4[k4];
            wi[4*k4+0]=v.x; wi[4*k4+1]=v.y; wi[4*k4+2]=v.z; wi[4*k4+3]=v.w;
        }
        const float4* wh4 = (const float4*)(w_hh + tau*HH);
        #pragma unroll
        for (int j4 = 0; j4 < HH/4; ++j4) {
            float4 v = wh4[j4];
            wh[4*j4+0]=v.x; wh[4*j4+1]=v.y; wh[4*j4+2]=v.z; wh[4*j4+3]=v.w;
        }
        bi = b_ih[tau]; bh = b_hh[tau];
    }
    if (tau >= G3) {
        const int k0 = (tau - G3)*2;
        float2 v = *(const float2*)(x + (size_t)(0*BB + b)*OBS + k0);
        xb[0][k0] = v.x; xb[0][k0+1] = v.y;
    }
    if (tau < HH) {
        float d0 = done[0*BB + b];
        hb[tau] = (1.0f - d0) * h0[b*HH + tau];   // done-mask of carried state
    }
    __syncthreads();

    float dnext = 0.f;
    for (int t = 0; t < TT; ++t) {
        const int cur = t & 1, nxt = cur ^ 1;

        // prefetch next timestep inputs (latency hidden under the dots)
        float2 xr = make_float2(0.f, 0.f);
        if (tau >= G3 && t+1 < TT) {
            const int k0 = (tau - G3)*2;
            xr = *(const float2*)(x + (size_t)((t+1)*BB + b)*OBS + k0);
        }
        if (tau < HH && t+1 < TT) dnext = done[(t+1)*BB + b];

        if (tau < G3) {
            // gh_g = w_hh[g,:] . h  (+b_hh)   -- 4 independent acc chains
            const float4* hb4 = (const float4*)hb;
            float a0=0.f, a1=0.f, a2=0.f, a3=0.f;
            #pragma unroll
            for (int j4 = 0; j4 < HH/4; ++j4) {
                float4 hv = hb4[j4];
                a0 = fmaf(hv.x, wh[4*j4+0], a0);
                a1 = fmaf(hv.y, wh[4*j4+1], a1);
                a2 = fmaf(hv.z, wh[4*j4+2], a2);
                a3 = fmaf(hv.w, wh[4*j4+3], a3);
            }
            float gh = bh + ((a0+a1)+(a2+a3));
            // gi_g = w_ih[g,:] . x_t  (+b_ih)
            const float4* xb4 = (const float4*)xb[cur];
            float g0=0.f, g1=0.f, g2=0.f, g3=0.f;
            #pragma unroll
            for (int k4 = 0; k4 < OBS/4; ++k4) {
                float4 xv = xb4[k4];
                g0 = fmaf(xv.x, wi[4*k4+0], g0);
                g1 = fmaf(xv.y, wi[4*k4+1], g1);
                g2 = fmaf(xv.z, wi[4*k4+2], g2);
                g3 = fmaf(xv.w, wi[4*k4+3], g3);
            }
            float gi = bi + ((g0+g1)+(g2+g3));
            if (tau < 2*HH) srz[tau] = gi + gh;               // r, z sums
            else { sinb[tau-2*HH] = gi; shnb[tau-2*HH] = gh; } // n kept split
        } else if (t+1 < TT) {
            const int k0 = (tau - G3)*2;
            xb[nxt][k0] = xr.x; xb[nxt][k0+1] = xr.y;
        }
        __syncthreads();   // (A) srz ready; hb/xb[cur] reads complete

        if (tau < HH) {
            float sr = srz[tau];
            float sz = srz[HH + tau];
            float r = 1.0f / (1.0f + expf(-sr));
            float z = 1.0f / (1.0f + expf(-sz));
            float n = tanhf(sinb[tau] + r * shnb[tau]);
            float hm = hb[tau];                 // already done-masked
            float hnew = (1.0f - z)*n + z*hm;
            float s = (hnew > 0.f) ? 1.f : ((hnew < 0.f) ? -1.f : 0.f);
            hidden[(size_t)(t*BB + b)*HH + tau] = (signed char)s;
            if (t == TT-1) state_out[b*HH + tau] = s;
            // carried state for t+1, masked by done[t+1]
            float hnext = (t+1 < TT && dnext != 0.f) ? 0.f : s;
            hb[tau] = hnext;
        }
        __syncthreads();   // (B) hb ready for next step
    }
}

// ---------------------------------------------------------------------------
// Fused 3-layer MLP head over cat=[hidden(s8, 64), x(f32, 128)].
// 512 threads, 256 rows/block (4 chunks x 64 rows), 8 lanes per row.
// Weights staged in LDS (w1 in two 96-wide K halves -> 59KB total LDS,
// 2 blocks/CU, 4 waves/SIMD). y1/y2 exchanged via stride-68 LDS (no bank
// conflicts on the per-row broadcast reads).
// ---------------------------------------------------------------------------
template<int NOUT>
__global__ __launch_bounds__(512, 2)
void mlp_kernel(const signed char* __restrict__ hidden, const float* __restrict__ x,
                const float* __restrict__ w1, const float* __restrict__ b1,
                const float* __restrict__ w2, const float* __restrict__ b2,
                const float* __restrict__ w3, const float* __restrict__ b3,
                float* __restrict__ out)
{
    __shared__ __align__(16) float wbuf[6144];     // w1-half [64][96] / w2 / w3
    __shared__ __align__(16) float y1buf[64*68];
    __shared__ __align__(16) float y2buf[64*68];
    const int tid = threadIdx.x;
    const int rl  = tid >> 3;   // row-in-chunk 0..63
    const int q   = tid & 7;    // lane within row

    for (int rc = 0; rc < 4; ++rc) {
        const int row = blockIdx.x*256 + rc*64 + rl;

        float acc[8];
        #pragma unroll
        for (int j = 0; j < 8; ++j) acc[j] = b1[q + 8*j];

        #pragma unroll
        for (int half = 0; half < 2; ++half) {
            __syncthreads();   // prior-phase LDS reads done before restage
            #pragma unroll
            for (int i = 0; i < 3; ++i) {           // stage w1 half [64][96]
                int flat = (tid + i*512)*4;
                int f = flat/96, kk = flat%96;
                *(float4*)&wbuf[flat] = *(const float4*)&w1[f*G3 + half*96 + kk];
            }
            __syncthreads();
            #pragma unroll
            for (int kc = 0; kc < 3; ++kc) {
                float cv[32];
                const int kg = half*96 + kc*32;     // global k base (compile-time)
                if (kg < 64) {
                    int4 h1 = *(const int4*)(hidden + (size_t)row*HH + kg);
                    int4 h2 = *(const int4*)(hidden + (size_t)row*HH + kg + 16);
                    int wbytes[8] = {h1.x,h1.y,h1.z,h1.w,h2.x,h2.y,h2.z,h2.w};
                    #pragma unroll
                    for (int u = 0; u < 8; ++u) {
                        cv[4*u+0] = (float)(signed char)(wbytes[u]);
                        cv[4*u+1] = (float)(signed char)(wbytes[u]>>8);
                        cv[4*u+2] = (float)(signed char)(wbytes[u]>>16);
                        cv[4*u+3] = (float)(signed char)(wbytes[u]>>24);
                    }
                } else {
                    const float4* xp = (const float4*)(x + (size_t)row*OBS + (kg - 64));
                    #pragma unroll
                    for (int u = 0; u < 8; ++u) {
                        float4 v = xp[u];
                        cv[4*u+0]=v.x; cv[4*u+1]=v.y; cv[4*u+2]=v.z; cv[4*u+3]=v.w;
                    }
                }
                #pragma unroll
                for (int j = 0; j < 8; ++j) {
                    const int f = q + 8*j;
                    const float4* wp = (const float4*)&wbuf[f*96 + kc*32];
                    float a = acc[j];
                    #pragma unroll
                    for (int k4 = 0; k4 < 8; ++k4) {
                        float4 wv = wp[k4];
                        a = fmaf(cv[4*k4+0], wv.x, a);
                        a = fmaf(cv[4*k4+1], wv.y, a);
                        a = fmaf(cv[4*k4+2], wv.z, a);
                        a = fmaf(cv[4*k4+3], wv.w, a);
                    }
                    acc[j] = a;
                }
            }
        }
        #pragma unroll
        for (int j = 0; j < 8; ++j) y1buf[rl*68 + q + 8*j] = tanhf(acc[j]);
        __syncthreads();

        #pragma unroll
        for (int i = 0; i < 2; ++i) {               // stage w2 [64][64]
            int flat = (tid + i*512)*4;
            *(float4*)&wbuf[flat] = *(const float4*)&w2[flat];
        }
        __syncthreads();

        float acc2[8];
        #pragma unroll
        for (int j = 0; j < 8; ++j) acc2[j] = b2[q + 8*j];
        {
            const float4* yp = (const float4*)&y1buf[rl*68];
            #pragma unroll
            for (int k4 = 0; k4 < 16; ++k4) {
                float4 yv = yp[k4];
                #pragma unroll
                for (int j = 0; j < 8; ++j) {
                    const int f = q + 8*j;
                    float4 wv = *(const float4*)&wbuf[f*64 + k4*4];
                    acc2[j] = fmaf(yv.x, wv.x, acc2[j]);
                    acc2[j] = fmaf(yv.y, wv.y, acc2[j]);
                    acc2[j] = fmaf(yv.z, wv.z, acc2[j]);
                    acc2[j] = fmaf(yv.w, wv.w, acc2[j]);
                }
            }
        }
        #pragma unroll
        for (int j = 0; j < 8; ++j) y2buf[rl*68 + q + 8*j] = tanhf(acc2[j]);
        __syncthreads();

        if (tid < NOUT*16) {                        // stage w3 [NOUT][64]
            *(float4*)&wbuf[tid*4] = *(const float4*)&w3[tid*4];
        }
        __syncthreads();

        #pragma unroll
        for (int oo = 0; oo < 2; ++oo) {
            const int o = q + oo*8;
            if (o < NOUT) {
                float a0 = 0.f, a1 = 0.f;
                const float4* yp = (const float4*)&y2buf[rl*68];
                const float4* wp = (const float4*)&wbuf[o*64];
                #pragma unroll
                for (int k4 = 0; k4 < 16; ++k4) {
                    float4 yv = yp[k4];
                    float4 wv = wp[k4];
                    a0 = fmaf(yv.x, wv.x, a0);
                    a0 = fmaf(yv.y, wv.y, a0);
                    a1 = fmaf(yv.z, wv.z, a1);
                    a1 = fmaf(yv.w, wv.w, a1);
                }
                out[(size_t)row*NOUT + o] = b3[o] + (a0 + a1);
            }
        }
        __syncthreads();   // before next rc restages w1
    }
}

extern "C" void kernel_launch(void* const* d_in, const int* in_sizes, int n_in,
                              void* d_out, int out_size, void* d_ws, size_t ws_size,
                              hipStream_t stream) {
    const float* x     = (const float*)d_in[0];
    const float* h0    = (const float*)d_in[1];
    const float* done  = (const float*)d_in[2];
    const float* w_ih  = (const float*)d_in[3];
    const float* w_hh  = (const float*)d_in[4];
    const float* b_ih  = (const float*)d_in[5];
    const float* b_hh  = (const float*)d_in[6];
    const float* a_w1  = (const float*)d_in[7];
    const float* a_b1  = (const float*)d_in[8];
    const float* a_w2  = (const float*)d_in[9];
    const float* a_b2  = (const float*)d_in[10];
    const float* a_w3  = (const float*)d_in[11];
    const float* a_b3  = (const float*)d_in[12];
    const float* c_w1  = (const float*)d_in[13];
    const float* c_b1  = (const float*)d_in[14];
    const float* c_w2  = (const float*)d_in[15];
    const float* c_b2  = (const float*)d_in[16];
    const float* c_w3  = (const float*)d_in[17];
    const float* c_b3  = (const float*)d_in[18];

    float* out    = (float*)d_out;
    float* logits = out;                       // [131072, 16]
    float* value  = out + (size_t)NROW*16;     // [131072]
    float* state  = value + NROW;              // [1, 256, 64]

    signed char* hidden = (signed char*)d_ws;  // [131072, 64] in {-1,0,1}

    scan_kernel<<<BB, 256, 0, stream>>>(x, h0, done, w_ih, w_hh, b_ih, b_hh,
                                        hidden, state);
    mlp_kernel<16><<<512, 512, 0, stream>>>(hidden, x, a_w1, a_b1, a_w2, a_b2,
                                            a_w3, a_b3, logits);
    mlp_kernel<1><<<512, 512, 0, stream>>>(hidden, x, c_w1, c_b1, c_w2, c_b2,
                                           c_w3, c_b3, value);
}

// Round 3
// 960.286 us; speedup vs baseline: 9.1860x; 9.1860x over previous
//
#include <hip/hip_runtime.h>
#include <math.h>

#define TT 512
#define BB 256
#define OBSZ 128
#define HH 64
#define G3 192
#define NROW (TT*BB)

// ---- fast transcendentals: ONLY used downstream of sign() (MLP heads) -----
__device__ __forceinline__ float fast_rcp(float x) {
    return __builtin_amdgcn_rcpf(x);
}
__device__ __forceinline__ float tanh_fast(float x) {
    float xc = fminf(fmaxf(x, -20.0f), 20.0f);   // clamp: avoid inf/inf NaN
    float e2 = __expf(2.0f * xc);
    return (e2 - 1.0f) * fast_rcp(e2 + 1.0f);
}

// ---------------------------------------------------------------------------
// Fused input-projection + sequential GRU scan. One block per batch element.
// 256 threads: tau<192 hold w_ih/w_hh rows in VGPRs; tau>=192 double-buffer x.
// All f32, libm expf/tanhf (precision-critical upstream of sign(); fast
// transcendentals here flip signs of near-zero h_new -> 0.45 absmax FAIL,
// measured round 2).
// ---------------------------------------------------------------------------
__global__ __launch_bounds__(256, 1)
void scan_kernel(const float* __restrict__ x, const float* __restrict__ h0,
                 const float* __restrict__ done,
                 const float* __restrict__ w_ih, const float* __restrict__ w_hh,
                 const float* __restrict__ b_ih, const float* __restrict__ b_hh,
                 signed char* __restrict__ hidden, float* __restrict__ state_out)
{
    const int b   = blockIdx.x;
    const int tau = threadIdx.x;

    __shared__ __align__(16) float xb[2][OBSZ];
    __shared__ __align__(16) float hb[HH];
    __shared__ __align__(16) float srz[2*HH];
    __shared__ __align__(16) float sinb[HH];
    __shared__ __align__(16) float shnb[HH];

    float wi[OBSZ];
    float wh[HH];
    float bi = 0.f, bh = 0.f;
    if (tau < G3) {
        const float4* wi4 = (const float4*)(w_ih + tau*OBSZ);
        #pragma unroll
        for (int k4 = 0; k4 < OBSZ/4; ++k4) {
            float4 v = wi4[k4];
            wi[4*k4+0]=v.x; wi[4*k4+1]=v.y; wi[4*k4+2]=v.z; wi[4*k4+3]=v.w;
        }
        const float4* wh4 = (const float4*)(w_hh + tau*HH);
        #pragma unroll
        for (int j4 = 0; j4 < HH/4; ++j4) {
            float4 v = wh4[j4];
            wh[4*j4+0]=v.x; wh[4*j4+1]=v.y; wh[4*j4+2]=v.z; wh[4*j4+3]=v.w;
        }
        bi = b_ih[tau]; bh = b_hh[tau];
    }
    if (tau >= G3) {
        const int k0 = (tau - G3)*2;
        float2 v = *(const float2*)(x + (size_t)(0*BB + b)*OBSZ + k0);
        xb[0][k0] = v.x; xb[0][k0+1] = v.y;
    }
    if (tau < HH) {
        float d0 = done[0*BB + b];
        hb[tau] = (1.0f - d0) * h0[b*HH + tau];
    }
    __syncthreads();

    float dnext = 0.f;
    for (int t = 0; t < TT; ++t) {
        const int cur = t & 1, nxt = cur ^ 1;

        float2 xr = make_float2(0.f, 0.f);
        if (tau >= G3 && t+1 < TT) {
            const int k0 = (tau - G3)*2;
            xr = *(const float2*)(x + (size_t)((t+1)*BB + b)*OBSZ + k0);
        }
        if (tau < HH && t+1 < TT) dnext = done[(t+1)*BB + b];

        if (tau < G3) {
            const float4* hb4 = (const float4*)hb;
            float a0=0.f, a1=0.f, a2=0.f, a3=0.f;
            #pragma unroll
            for (int j4 = 0; j4 < HH/4; ++j4) {
                float4 hv = hb4[j4];
                a0 = fmaf(hv.x, wh[4*j4+0], a0);
                a1 = fmaf(hv.y, wh[4*j4+1], a1);
                a2 = fmaf(hv.z, wh[4*j4+2], a2);
                a3 = fmaf(hv.w, wh[4*j4+3], a3);
            }
            float gh = bh + ((a0+a1)+(a2+a3));
            const float4* xb4 = (const float4*)xb[cur];
            float g0=0.f, g1=0.f, g2=0.f, g3=0.f;
            #pragma unroll
            for (int k4 = 0; k4 < OBSZ/4; ++k4) {
                float4 xv = xb4[k4];
                g0 = fmaf(xv.x, wi[4*k4+0], g0);
                g1 = fmaf(xv.y, wi[4*k4+1], g1);
                g2 = fmaf(xv.z, wi[4*k4+2], g2);
                g3 = fmaf(xv.w, wi[4*k4+3], g3);
            }
            float gi = bi + ((g0+g1)+(g2+g3));
            if (tau < 2*HH) srz[tau] = gi + gh;
            else { sinb[tau-2*HH] = gi; shnb[tau-2*HH] = gh; }
        } else if (t+1 < TT) {
            const int k0 = (tau - G3)*2;
            xb[nxt][k0] = xr.x; xb[nxt][k0+1] = xr.y;
        }
        __syncthreads();   // (A) srz/sin/shn ready; hb/xb[cur] reads complete

        if (tau < HH) {
            float sr = srz[tau];
            float sz = srz[HH + tau];
            float r = 1.0f / (1.0f + expf(-sr));   // libm: precision-critical
            float z = 1.0f / (1.0f + expf(-sz));
            float n = tanhf(sinb[tau] + r * shnb[tau]);
            float hm = hb[tau];
            float hnew = (1.0f - z)*n + z*hm;
            float s = (hnew > 0.f) ? 1.f : ((hnew < 0.f) ? -1.f : 0.f);
            hidden[(size_t)(t*BB + b)*HH + tau] = (signed char)s;
            if (t == TT-1) state_out[b*HH + tau] = s;
            hb[tau] = (t+1 < TT && dnext != 0.f) ? 0.f : s;
        }
        __syncthreads();   // (B) hb ready for next step
    }
}

// ---------------------------------------------------------------------------
// Fused 3-layer MLP over cat=[hidden(s8,64), x(f32,128)].
// 256 threads (4 waves), 2 chunks x 128 rows/block. 8 feature-lanes x 4 rows
// per lane-group; k streamed in 8-float chunks (cv[4][8] live: no spill).
// LDS strides 100/68 floats (== 4 mod 32 banks -> conflict-free b128 reads;
// 8 same-q lanes read identical addresses -> broadcast).
// tanh_fast is safe here (downstream of sign; linear error propagation).
// ---------------------------------------------------------------------------
template<int NOUT>
__global__ __launch_bounds__(256, 2)
void mlp_kernel(const signed char* __restrict__ hidden, const float* __restrict__ x,
                const float* __restrict__ w1, const float* __restrict__ b1,
                const float* __restrict__ w2, const float* __restrict__ b2,
                const float* __restrict__ w3, const float* __restrict__ b3,
                float* __restrict__ out)
{
    __shared__ __align__(16) float wbuf[64*100];   // 25.6 KB (w1-half / w2 / w3)
    __shared__ __align__(16) float ybuf[128*68];   // 34.8 KB (y1 then y2)
    const int tid = threadIdx.x;
    const int g   = tid >> 3;   // lane-group 0..31 (4 rows each)
    const int q   = tid & 7;    // feature lane

    float bv1[8], bv2[8];
    #pragma unroll
    for (int j = 0; j < 8; ++j) { bv1[j] = b1[q + 8*j]; bv2[j] = b2[q + 8*j]; }

    for (int chunk = 0; chunk < 2; ++chunk) {
        const int row0 = blockIdx.x*256 + chunk*128 + g*4;

        float acc[8][4];
        #pragma unroll
        for (int j = 0; j < 8; ++j)
            #pragma unroll
            for (int r = 0; r < 4; ++r) acc[j][r] = bv1[j];

        // 32 fma per (j x r) block against one 8-wide k-chunk of weights
        auto dot8 = [&](float (&cv)[4][8], int colbase) {
            #pragma unroll
            for (int j = 0; j < 8; ++j) {
                const float* wp = &wbuf[(q + 8*j)*100 + colbase];
                float4 w0 = *(const float4*)wp;
                float4 w1v = *(const float4*)(wp + 4);
                #pragma unroll
                for (int r = 0; r < 4; ++r) {
                    acc[j][r] = fmaf(cv[r][0], w0.x,  acc[j][r]);
                    acc[j][r] = fmaf(cv[r][1], w0.y,  acc[j][r]);
                    acc[j][r] = fmaf(cv[r][2], w0.z,  acc[j][r]);
                    acc[j][r] = fmaf(cv[r][3], w0.w,  acc[j][r]);
                    acc[j][r] = fmaf(cv[r][4], w1v.x, acc[j][r]);
                    acc[j][r] = fmaf(cv[r][5], w1v.y, acc[j][r]);
                    acc[j][r] = fmaf(cv[r][6], w1v.z, acc[j][r]);
                    acc[j][r] = fmaf(cv[r][7], w1v.w, acc[j][r]);
                }
            }
        };

        #pragma unroll
        for (int half = 0; half < 2; ++half) {
            __syncthreads();   // prior wbuf/ybuf readers done before restage
            #pragma unroll
            for (int i = 0; i < 6; ++i) {          // stage w1 half [64][96]->stride 100
                int v = tid + i*256;
                int f = v / 24, k4 = v % 24;
                *(float4*)&wbuf[f*100 + k4*4] =
                    *(const float4*)&w1[f*G3 + half*96 + k4*4];
            }
            __syncthreads();

            if (half == 0) {
                for (int kc = 0; kc < 8; ++kc) {   // k 0..63: hidden (s8)
                    float cv[4][8];
                    #pragma unroll
                    for (int r = 0; r < 4; ++r) {
                        uint2 hv = *(const uint2*)(hidden + (size_t)(row0+r)*HH + kc*8);
                        cv[r][0] = (float)(signed char)(hv.x);
                        cv[r][1] = (float)(signed char)(hv.x >> 8);
                        cv[r][2] = (float)(signed char)(hv.x >> 16);
                        cv[r][3] = (float)(signed char)(hv.x >> 24);
                        cv[r][4] = (float)(signed char)(hv.y);
                        cv[r][5] = (float)(signed char)(hv.y >> 8);
                        cv[r][6] = (float)(signed char)(hv.y >> 16);
                        cv[r][7] = (float)(signed char)(hv.y >> 24);
                    }
                    dot8(cv, kc*8);
                }
                for (int kc = 0; kc < 4; ++kc) {   // k 64..95: x[0..31]
                    float cv[4][8];
                    #pragma unroll
                    for (int r = 0; r < 4; ++r) {
                        const float* xp = x + (size_t)(row0+r)*OBSZ + kc*8;
                        float4 a = *(const float4*)xp;
                        float4 c = *(const float4*)(xp + 4);
                        cv[r][0]=a.x; cv[r][1]=a.y; cv[r][2]=a.z; cv[r][3]=a.w;
                        cv[r][4]=c.x; cv[r][5]=c.y; cv[r][6]=c.z; cv[r][7]=c.w;
                    }
                    dot8(cv, 64 + kc*8);
                }
            } else {
                for (int kc = 0; kc < 12; ++kc) {  // k 96..191: x[32..127]
                    float cv[4][8];
                    #pragma unroll
                    for (int r = 0; r < 4; ++r) {
                        const float* xp = x + (size_t)(row0+r)*OBSZ + 32 + kc*8;
                        float4 a = *(const float4*)xp;
                        float4 c = *(const float4*)(xp + 4);
                        cv[r][0]=a.x; cv[r][1]=a.y; cv[r][2]=a.z; cv[r][3]=a.w;
                        cv[r][4]=c.x; cv[r][5]=c.y; cv[r][6]=c.z; cv[r][7]=c.w;
                    }
                    dot8(cv, kc*8);
                }
            }
        }

        #pragma unroll
        for (int j = 0; j < 8; ++j)
            #pragma unroll
            for (int r = 0; r < 4; ++r)
                ybuf[(g*4+r)*68 + q + 8*j] = tanh_fast(acc[j][r]);
        __syncthreads();

        #pragma unroll
        for (int i = 0; i < 4; ++i) {              // stage w2 [64][64]->stride 68
            int v = tid + i*256;
            int f = v >> 4, k4 = v & 15;
            *(float4*)&wbuf[f*68 + k4*4] = *(const float4*)&w2[f*HH + k4*4];
        }
        __syncthreads();

        float acc2[8][4];
        #pragma unroll
        for (int j = 0; j < 8; ++j)
            #pragma unroll
            for (int r = 0; r < 4; ++r) acc2[j][r] = bv2[j];

        for (int kc = 0; kc < 8; ++kc) {
            float cv[4][8];
            #pragma unroll
            for (int r = 0; r < 4; ++r) {
                const float* yp = &ybuf[(g*4+r)*68 + kc*8];
                float4 a = *(const float4*)yp;
                float4 c = *(const float4*)(yp + 4);
                cv[r][0]=a.x; cv[r][1]=a.y; cv[r][2]=a.z; cv[r][3]=a.w;
                cv[r][4]=c.x; cv[r][5]=c.y; cv[r][6]=c.z; cv[r][7]=c.w;
            }
            #pragma unroll
            for (int j = 0; j < 8; ++j) {
                const float* wp = &wbuf[(q + 8*j)*68 + kc*8];
                float4 w0 = *(const float4*)wp;
                float4 w1v = *(const float4*)(wp + 4);
                #pragma unroll
                for (int r = 0; r < 4; ++r) {
                    acc2[j][r] = fmaf(cv[r][0], w0.x,  acc2[j][r]);
                    acc2[j][r] = fmaf(cv[r][1], w0.y,  acc2[j][r]);
                    acc2[j][r] = fmaf(cv[r][2], w0.z,  acc2[j][r]);
                    acc2[j][r] = fmaf(cv[r][3], w0.w,  acc2[j][r]);
                    acc2[j][r] = fmaf(cv[r][4], w1v.x, acc2[j][r]);
                    acc2[j][r] = fmaf(cv[r][5], w1v.y, acc2[j][r]);
                    acc2[j][r] = fmaf(cv[r][6], w1v.z, acc2[j][r]);
                    acc2[j][r] = fmaf(cv[r][7], w1v.w, acc2[j][r]);
                }
            }
        }
        __syncthreads();   // all y1 reads done before overwrite

        #pragma unroll
        for (int j = 0; j < 8; ++j)
            #pragma unroll
            for (int r = 0; r < 4; ++r)
                ybuf[(g*4+r)*68 + q + 8*j] = tanh_fast(acc2[j][r]);
        if (tid < NOUT*16) {                       // stage w3 [NOUT][64]->stride 68
            int f = tid >> 4, k4 = tid & 15;
            *(float4*)&wbuf[f*68 + k4*4] = *(const float4*)&w3[f*HH + k4*4];
        }
        __syncthreads();

        #pragma unroll
        for (int oo = 0; oo < (NOUT + 7)/8; ++oo) {
            const int o = q + 8*oo;
            if (o < NOUT) {
                #pragma unroll
                for (int r = 0; r < 4; ++r) {
                    const float* yp = &ybuf[(g*4+r)*68];
                    const float* wp = &wbuf[o*68];
                    float s0=0.f, s1=0.f, s2=0.f, s3=0.f;
                    #pragma unroll
                    for (int k4 = 0; k4 < 16; ++k4) {
                        float4 yv = *(const float4*)(yp + k4*4);
                        float4 wv = *(const float4*)(wp + k4*4);
                        s0 = fmaf(yv.x, wv.x, s0);
                        s1 = fmaf(yv.y, wv.y, s1);
                        s2 = fmaf(yv.z, wv.z, s2);
                        s3 = fmaf(yv.w, wv.w, s3);
                    }
                    out[(size_t)(row0+r)*NOUT + o] = b3[o] + ((s0+s1)+(s2+s3));
                }
            }
        }
        __syncthreads();   // layer3 ybuf/wbuf reads done before next chunk
    }
}

extern "C" void kernel_launch(void* const* d_in, const int* in_sizes, int n_in,
                              void* d_out, int out_size, void* d_ws, size_t ws_size,
                              hipStream_t stream) {
    const float* x     = (const float*)d_in[0];
    const float* h0    = (const float*)d_in[1];
    const float* done  = (const float*)d_in[2];
    const float* w_ih  = (const float*)d_in[3];
    const float* w_hh  = (const float*)d_in[4];
    const float* b_ih  = (const float*)d_in[5];
    const float* b_hh  = (const float*)d_in[6];
    const float* a_w1  = (const float*)d_in[7];
    const float* a_b1  = (const float*)d_in[8];
    const float* a_w2  = (const float*)d_in[9];
    const float* a_b2  = (const float*)d_in[10];
    const float* a_w3  = (const float*)d_in[11];
    const float* a_b3  = (const float*)d_in[12];
    const float* c_w1  = (const float*)d_in[13];
    const float* c_b1  = (const float*)d_in[14];
    const float* c_w2  = (const float*)d_in[15];
    const float* c_b2  = (const float*)d_in[16];
    const float* c_w3  = (const float*)d_in[17];
    const float* c_b3  = (const float*)d_in[18];

    float* out    = (float*)d_out;
    float* logits = out;                       // [131072, 16]
    float* value  = out + (size_t)NROW*16;     // [131072]
    float* state  = value + NROW;              // [1, 256, 64]

    signed char* hidden = (signed char*)d_ws;  // [131072, 64] in {-1,0,1}

    scan_kernel<<<BB, 256, 0, stream>>>(x, h0, done, w_ih, w_hh, b_ih, b_hh,
                                        hidden, state);
    mlp_kernel<16><<<512, 256, 0, stream>>>(hidden, x, a_w1, a_b1, a_w2, a_b2,
                                            a_w3, a_b3, logits);
    mlp_kernel<1><<<512, 256, 0, stream>>>(hidden, x, c_w1, c_b1, c_w2, c_b2,
                                           c_w3, c_b3, value);
}

// Round 4
// 835.872 us; speedup vs baseline: 10.5532x; 1.1488x over previous
//
#include <hip/hip_runtime.h>
#include <math.h>

#define TT 512
#define BB 256
#define OBSZ 128
#define HH 64
#define G3 192
#define NROW (TT*BB)

// ---- fast transcendentals: ONLY used downstream of sign() (MLP heads) -----
__device__ __forceinline__ float fast_rcp(float x) {
    return __builtin_amdgcn_rcpf(x);
}
__device__ __forceinline__ float tanh_fast(float x) {
    float xc = fminf(fmaxf(x, -20.0f), 20.0f);   // clamp: avoid inf/inf NaN
    float e2 = __expf(2.0f * xc);
    return (e2 - 1.0f) * fast_rcp(e2 + 1.0f);
}

// ---------------------------------------------------------------------------
// Fused input-projection + sequential GRU scan. One block per batch element.
// 256 threads:
//   tau <  192 : g-threads — hold w_ih row (128 f32) + w_hh row (64 f32) in
//                VGPRs; compute gi+gh dots each step. waves_per_eu(1,1) pins
//                the register budget to 512/wave so the weight arrays are NOT
//                spilled (round-3 CSV showed VGPR_Count=120 -> spilled ->
//                L2-bound at 3820 cy/step).
//   tau >= 192 : helper/gate threads — double-buffer x rows AND run the gate
//                nonlinearity (libm expf/tanhf; precision-critical upstream
//                of sign(); fast versions flipped signs -> 0.45 FAIL, r2).
// All arithmetic (chain order, pairing) bit-identical to the passing round 3.
// ---------------------------------------------------------------------------
__global__ __launch_bounds__(256, 1)
__attribute__((amdgpu_waves_per_eu(1, 1)))
void scan_kernel(const float* __restrict__ x, const float* __restrict__ h0,
                 const float* __restrict__ done,
                 const float* __restrict__ w_ih, const float* __restrict__ w_hh,
                 const float* __restrict__ b_ih, const float* __restrict__ b_hh,
                 signed char* __restrict__ hidden, float* __restrict__ state_out)
{
    const int b   = blockIdx.x;
    const int tau = threadIdx.x;

    __shared__ __align__(16) float xb[2][OBSZ];
    __shared__ __align__(16) float hb[HH];
    __shared__ __align__(16) float srz[2*HH];
    __shared__ __align__(16) float sinb[HH];
    __shared__ __align__(16) float shnb[HH];

    float4 wi4[OBSZ/4];
    float4 wh4[HH/4];
    float bi = 0.f, bh = 0.f;
    if (tau < G3) {
        const float4* wip = (const float4*)(w_ih + tau*OBSZ);
        #pragma unroll
        for (int k4 = 0; k4 < OBSZ/4; ++k4) wi4[k4] = wip[k4];
        const float4* whp = (const float4*)(w_hh + tau*HH);
        #pragma unroll
        for (int j4 = 0; j4 < HH/4; ++j4) wh4[j4] = whp[j4];
        bi = b_ih[tau]; bh = b_hh[tau];
    } else {
        const int hl = tau - G3;          // helper/gate thread: hidden dim hl*2 staging, dim hl gating
        const int k0 = hl*2;
        float2 v = *(const float2*)(x + (size_t)(0*BB + b)*OBSZ + k0);
        xb[0][k0] = v.x; xb[0][k0+1] = v.y;
        float d0 = done[0*BB + b];
        hb[hl] = (1.0f - d0) * h0[b*HH + hl];
    }
    __syncthreads();

    float dnext = 0.f;
    for (int t = 0; t < TT; ++t) {
        const int cur = t & 1, nxt = cur ^ 1;

        if (tau < G3) {
            // ---- gh = w_hh[g,:] . h (+b_hh): 4 independent chains, order
            //      identical to round 3 ----
            const float4* hb4 = (const float4*)hb;
            float a0=0.f, a1=0.f, a2=0.f, a3=0.f;
            #pragma unroll
            for (int j4 = 0; j4 < HH/4; ++j4) {
                float4 hv = hb4[j4];
                a0 = fmaf(hv.x, wh4[j4].x, a0);
                a1 = fmaf(hv.y, wh4[j4].y, a1);
                a2 = fmaf(hv.z, wh4[j4].z, a2);
                a3 = fmaf(hv.w, wh4[j4].w, a3);
            }
            float gh = bh + ((a0+a1)+(a2+a3));
            // ---- gi = w_ih[g,:] . x_t (+b_ih) ----
            const float4* xb4 = (const float4*)xb[cur];
            float g0=0.f, g1=0.f, g2=0.f, g3=0.f;
            #pragma unroll
            for (int k4 = 0; k4 < OBSZ/4; ++k4) {
                float4 xv = xb4[k4];
                g0 = fmaf(xv.x, wi4[k4].x, g0);
                g1 = fmaf(xv.y, wi4[k4].y, g1);
                g2 = fmaf(xv.z, wi4[k4].z, g2);
                g3 = fmaf(xv.w, wi4[k4].w, g3);
            }
            float gi = bi + ((g0+g1)+(g2+g3));
            if (tau < 2*HH) srz[tau] = gi + gh;
            else { sinb[tau-2*HH] = gi; shnb[tau-2*HH] = gh; }
        } else {
            // helper/gate thread: prefetch next x row and next done flag
            const int hl = tau - G3;
            if (t+1 < TT) {
                const int k0 = hl*2;
                float2 xr = *(const float2*)(x + (size_t)((t+1)*BB + b)*OBSZ + k0);
                xb[nxt][k0] = xr.x; xb[nxt][k0+1] = xr.y;
                dnext = done[(t+1)*BB + b];
            }
        }
        __syncthreads();   // (A) srz/sin/shn ready; hb/xb[cur] reads complete

        if (tau >= G3) {
            const int hl = tau - G3;
            float sr = srz[hl];
            float sz = srz[HH + hl];
            float r = 1.0f / (1.0f + expf(-sr));   // libm: precision-critical
            float z = 1.0f / (1.0f + expf(-sz));
            float n = tanhf(sinb[hl] + r * shnb[hl]);
            float hm = hb[hl];
            float hnew = (1.0f - z)*n + z*hm;
            float s = (hnew > 0.f) ? 1.f : ((hnew < 0.f) ? -1.f : 0.f);
            hidden[(size_t)(t*BB + b)*HH + hl] = (signed char)s;
            if (t == TT-1) state_out[b*HH + hl] = s;
            hb[hl] = (t+1 < TT && dnext != 0.f) ? 0.f : s;
        }
        __syncthreads();   // (B) hb ready for next step
    }
}

// ---------------------------------------------------------------------------
// Fused 3-layer MLP over cat=[hidden(s8,64), x(f32,128)].  (unchanged, r3)
// ---------------------------------------------------------------------------
template<int NOUT>
__global__ __launch_bounds__(256, 2)
void mlp_kernel(const signed char* __restrict__ hidden, const float* __restrict__ x,
                const float* __restrict__ w1, const float* __restrict__ b1,
                const float* __restrict__ w2, const float* __restrict__ b2,
                const float* __restrict__ w3, const float* __restrict__ b3,
                float* __restrict__ out)
{
    __shared__ __align__(16) float wbuf[64*100];   // 25.6 KB (w1-half / w2 / w3)
    __shared__ __align__(16) float ybuf[128*68];   // 34.8 KB (y1 then y2)
    const int tid = threadIdx.x;
    const int g   = tid >> 3;   // lane-group 0..31 (4 rows each)
    const int q   = tid & 7;    // feature lane

    float bv1[8], bv2[8];
    #pragma unroll
    for (int j = 0; j < 8; ++j) { bv1[j] = b1[q + 8*j]; bv2[j] = b2[q + 8*j]; }

    for (int chunk = 0; chunk < 2; ++chunk) {
        const int row0 = blockIdx.x*256 + chunk*128 + g*4;

        float acc[8][4];
        #pragma unroll
        for (int j = 0; j < 8; ++j)
            #pragma unroll
            for (int r = 0; r < 4; ++r) acc[j][r] = bv1[j];

        auto dot8 = [&](float (&cv)[4][8], int colbase) {
            #pragma unroll
            for (int j = 0; j < 8; ++j) {
                const float* wp = &wbuf[(q + 8*j)*100 + colbase];
                float4 w0 = *(const float4*)wp;
                float4 w1v = *(const float4*)(wp + 4);
                #pragma unroll
                for (int r = 0; r < 4; ++r) {
                    acc[j][r] = fmaf(cv[r][0], w0.x,  acc[j][r]);
                    acc[j][r] = fmaf(cv[r][1], w0.y,  acc[j][r]);
                    acc[j][r] = fmaf(cv[r][2], w0.z,  acc[j][r]);
                    acc[j][r] = fmaf(cv[r][3], w0.w,  acc[j][r]);
                    acc[j][r] = fmaf(cv[r][4], w1v.x, acc[j][r]);
                    acc[j][r] = fmaf(cv[r][5], w1v.y, acc[j][r]);
                    acc[j][r] = fmaf(cv[r][6], w1v.z, acc[j][r]);
                    acc[j][r] = fmaf(cv[r][7], w1v.w, acc[j][r]);
                }
            }
        };

        #pragma unroll
        for (int half = 0; half < 2; ++half) {
            __syncthreads();   // prior wbuf/ybuf readers done before restage
            #pragma unroll
            for (int i = 0; i < 6; ++i) {          // stage w1 half [64][96]->stride 100
                int v = tid + i*256;
                int f = v / 24, k4 = v % 24;
                *(float4*)&wbuf[f*100 + k4*4] =
                    *(const float4*)&w1[f*G3 + half*96 + k4*4];
            }
            __syncthreads();

            if (half == 0) {
                for (int kc = 0; kc < 8; ++kc) {   // k 0..63: hidden (s8)
                    float cv[4][8];
                    #pragma unroll
                    for (int r = 0; r < 4; ++r) {
                        uint2 hv = *(const uint2*)(hidden + (size_t)(row0+r)*HH + kc*8);
                        cv[r][0] = (float)(signed char)(hv.x);
                        cv[r][1] = (float)(signed char)(hv.x >> 8);
                        cv[r][2] = (float)(signed char)(hv.x >> 16);
                        cv[r][3] = (float)(signed char)(hv.x >> 24);
                        cv[r][4] = (float)(signed char)(hv.y);
                        cv[r][5] = (float)(signed char)(hv.y >> 8);
                        cv[r][6] = (float)(signed char)(hv.y >> 16);
                        cv[r][7] = (float)(signed char)(hv.y >> 24);
                    }
                    dot8(cv, kc*8);
                }
                for (int kc = 0; kc < 4; ++kc) {   // k 64..95: x[0..31]
                    float cv[4][8];
                    #pragma unroll
                    for (int r = 0; r < 4; ++r) {
                        const float* xp = x + (size_t)(row0+r)*OBSZ + kc*8;
                        float4 a = *(const float4*)xp;
                        float4 c = *(const float4*)(xp + 4);
                        cv[r][0]=a.x; cv[r][1]=a.y; cv[r][2]=a.z; cv[r][3]=a.w;
                        cv[r][4]=c.x; cv[r][5]=c.y; cv[r][6]=c.z; cv[r][7]=c.w;
                    }
                    dot8(cv, 64 + kc*8);
                }
            } else {
                for (int kc = 0; kc < 12; ++kc) {  // k 96..191: x[32..127]
                    float cv[4][8];
                    #pragma unroll
                    for (int r = 0; r < 4; ++r) {
                        const float* xp = x + (size_t)(row0+r)*OBSZ + 32 + kc*8;
                        float4 a = *(const float4*)xp;
                        float4 c = *(const float4*)(xp + 4);
                        cv[r][0]=a.x; cv[r][1]=a.y; cv[r][2]=a.z; cv[r][3]=a.w;
                        cv[r][4]=c.x; cv[r][5]=c.y; cv[r][6]=c.z; cv[r][7]=c.w;
                    }
                    dot8(cv, kc*8);
                }
            }
        }

        #pragma unroll
        for (int j = 0; j < 8; ++j)
            #pragma unroll
            for (int r = 0; r < 4; ++r)
                ybuf[(g*4+r)*68 + q + 8*j] = tanh_fast(acc[j][r]);
        __syncthreads();

        #pragma unroll
        for (int i = 0; i < 4; ++i) {              // stage w2 [64][64]->stride 68
            int v = tid + i*256;
            int f = v >> 4, k4 = v & 15;
            *(float4*)&wbuf[f*68 + k4*4] = *(const float4*)&w2[f*HH + k4*4];
        }
        __syncthreads();

        float acc2[8][4];
        #pragma unroll
        for (int j = 0; j < 8; ++j)
            #pragma unroll
            for (int r = 0; r < 4; ++r) acc2[j][r] = bv2[j];

        for (int kc = 0; kc < 8; ++kc) {
            float cv[4][8];
            #pragma unroll
            for (int r = 0; r < 4; ++r) {
                const float* yp = &ybuf[(g*4+r)*68 + kc*8];
                float4 a = *(const float4*)yp;
                float4 c = *(const float4*)(yp + 4);
                cv[r][0]=a.x; cv[r][1]=a.y; cv[r][2]=a.z; cv[r][3]=a.w;
                cv[r][4]=c.x; cv[r][5]=c.y; cv[r][6]=c.z; cv[r][7]=c.w;
            }
            #pragma unroll
            for (int j = 0; j < 8; ++j) {
                const float* wp = &wbuf[(q + 8*j)*68 + kc*8];
                float4 w0 = *(const float4*)wp;
                float4 w1v = *(const float4*)(wp + 4);
                #pragma unroll
                for (int r = 0; r < 4; ++r) {
                    acc2[j][r] = fmaf(cv[r][0], w0.x,  acc2[j][r]);
                    acc2[j][r] = fmaf(cv[r][1], w0.y,  acc2[j][r]);
                    acc2[j][r] = fmaf(cv[r][2], w0.z,  acc2[j][r]);
                    acc2[j][r] = fmaf(cv[r][3], w0.w,  acc2[j][r]);
                    acc2[j][r] = fmaf(cv[r][4], w1v.x, acc2[j][r]);
                    acc2[j][r] = fmaf(cv[r][5], w1v.y, acc2[j][r]);
                    acc2[j][r] = fmaf(cv[r][6], w1v.z, acc2[j][r]);
                    acc2[j][r] = fmaf(cv[r][7], w1v.w, acc2[j][r]);
                }
            }
        }
        __syncthreads();   // all y1 reads done before overwrite

        #pragma unroll
        for (int j = 0; j < 8; ++j)
            #pragma unroll
            for (int r = 0; r < 4; ++r)
                ybuf[(g*4+r)*68 + q + 8*j] = tanh_fast(acc2[j][r]);
        if (tid < NOUT*16) {                       // stage w3 [NOUT][64]->stride 68
            int f = tid >> 4, k4 = tid & 15;
            *(float4*)&wbuf[f*68 + k4*4] = *(const float4*)&w3[f*HH + k4*4];
        }
        __syncthreads();

        #pragma unroll
        for (int oo = 0; oo < (NOUT + 7)/8; ++oo) {
            const int o = q + 8*oo;
            if (o < NOUT) {
                #pragma unroll
                for (int r = 0; r < 4; ++r) {
                    const float* yp = &ybuf[(g*4+r)*68];
                    const float* wp = &wbuf[o*68];
                    float s0=0.f, s1=0.f, s2=0.f, s3=0.f;
                    #pragma unroll
                    for (int k4 = 0; k4 < 16; ++k4) {
                        float4 yv = *(const float4*)(yp + k4*4);
                        float4 wv = *(const float4*)(wp + k4*4);
                        s0 = fmaf(yv.x, wv.x, s0);
                        s1 = fmaf(yv.y, wv.y, s1);
                        s2 = fmaf(yv.z, wv.z, s2);
                        s3 = fmaf(yv.w, wv.w, s3);
                    }
                    out[(size_t)(row0+r)*NOUT + o] = b3[o] + ((s0+s1)+(s2+s3));
                }
            }
        }
        __syncthreads();   // layer3 ybuf/wbuf reads done before next chunk
    }
}

extern "C" void kernel_launch(void* const* d_in, const int* in_sizes, int n_in,
                              void* d_out, int out_size, void* d_ws, size_t ws_size,
                              hipStream_t stream) {
    const float* x     = (const float*)d_in[0];
    const float* h0    = (const float*)d_in[1];
    const float* done  = (const float*)d_in[2];
    const float* w_ih  = (const float*)d_in[3];
    const float* w_hh  = (const float*)d_in[4];
    const float* b_ih  = (const float*)d_in[5];
    const float* b_hh  = (const float*)d_in[6];
    const float* a_w1  = (const float*)d_in[7];
    const float* a_b1  = (const float*)d_in[8];
    const float* a_w2  = (const float*)d_in[9];
    const float* a_b2  = (const float*)d_in[10];
    const float* a_w3  = (const float*)d_in[11];
    const float* a_b3  = (const float*)d_in[12];
    const float* c_w1  = (const float*)d_in[13];
    const float* c_b1  = (const float*)d_in[14];
    const float* c_w2  = (const float*)d_in[15];
    const float* c_b2  = (const float*)d_in[16];
    const float* c_w3  = (const float*)d_in[17];
    const float* c_b3  = (const float*)d_in[18];

    float* out    = (float*)d_out;
    float* logits = out;                       // [131072, 16]
    float* value  = out + (size_t)NROW*16;     // [131072]
    float* state  = value + NROW;              // [1, 256, 64]

    signed char* hidden = (signed char*)d_ws;  // [131072, 64] in {-1,0,1}

    scan_kernel<<<BB, 256, 0, stream>>>(x, h0, done, w_ih, w_hh, b_ih, b_hh,
                                        hidden, state);
    mlp_kernel<16><<<512, 256, 0, stream>>>(hidden, x, a_w1, a_b1, a_w2, a_b2,
                                            a_w3, a_b3, logits);
    mlp_kernel<1><<<512, 256, 0, stream>>>(hidden, x, c_w1, c_b1, c_w2, c_b2,
                                           c_w3, c_b3, value);
}